// Round 10
// baseline (1036.205 us; speedup 1.0000x reference)
//
#include <hip/hip_runtime.h>
#include <stdint.h>

#define DIM 384
#define WIN 64
#define HEADS 12
#define HD 32
#define NWIN 4096

typedef _Float16 f16;
typedef unsigned int u32;
typedef _Float16 half8 __attribute__((ext_vector_type(8)));
typedef _Float16 half4 __attribute__((ext_vector_type(4)));
typedef float floatx4 __attribute__((ext_vector_type(4)));

#define AS1 __attribute__((address_space(1)))
#define AS3 __attribute__((address_space(3)))

__device__ __forceinline__ void gl_lds16(const void* g, void* l) {
    __builtin_amdgcn_global_load_lds((const AS1 u32*)g, (AS3 u32*)l, 16, 0, 0);
}

// LDS segment byte offsets (total 161792 < 163840)
#define SEG_A    0        // 8 KB  : A stage dbuf (2x4KB)
#define SEG_B    8192     // 48 KB : B stage dbuf (2x24KB); q_lds aliases here after Q phase
#define SEG_K    57344    // 48 KB : k row-major XOR
#define SEG_V    106496   // 48 KB : v transposed [d][m] XOR
#define SEG_BIAS 155648   // 6 KB  : bias [12][128] f32

// q/k: element (n,d) -> byte offset within seg (row-major, 16B-slot XOR by n&7)
__device__ __forceinline__ int qk_off(int n, int d) {
    return n * 768 + ((((d >> 3) ^ (n & 7))) << 4) + ((d & 7) << 1);
}
// v_t: element (d,m) -> byte offset (row d, 16B-slot XOR by d&7)
__device__ __forceinline__ int vt_off(int d, int m) {
    return d * 128 + ((((m >> 3) ^ (d & 7))) << 4) + ((m & 7) << 1);
}

// ---------------- fp32 -> fp16 convert (proj weights) ----------------
__global__ void cvt_kernel(const float* __restrict__ in, f16* __restrict__ out, long n4) {
    long i = (long)blockIdx.x * blockDim.x + threadIdx.x;
    const long stride = (long)gridDim.x * blockDim.x;
    for (; i < n4; i += stride) {
        float4 v = ((const float4*)in)[i];
        half4 h;
        h[0] = (f16)v.x; h[1] = (f16)v.y; h[2] = (f16)v.z; h[3] = (f16)v.w;
        ((half4*)out)[i] = h;
    }
}

// ---------------- pack qkv_w fp32[1152][384] -> Bp[p 3][s 12][kc 4][u 384][8] f16
// q (p=0) pre-scaled by 32^-0.5
__global__ void pack_w_kernel(const float* __restrict__ w, f16* __restrict__ Bp) {
    const int t = blockIdx.x * 256 + threadIdx.x;      // 55296 chunks
    const int p = t / 18432;
    const int r1 = t % 18432;
    const int s = r1 / 1536;
    const int r2 = r1 % 1536;
    const int kc = r2 / 384, u = r2 % 384;
    const float sc = (p == 0) ? 0.17677669529663687f : 1.0f;
    const float* sp = w + (size_t)(p * 384 + u) * DIM + s * 32 + kc * 8;
    float4 a = *(const float4*)sp;
    float4 b = *(const float4*)(sp + 4);
    half8 o;
    o[0] = (f16)(a.x * sc); o[1] = (f16)(a.y * sc); o[2] = (f16)(a.z * sc); o[3] = (f16)(a.w * sc);
    o[4] = (f16)(b.x * sc); o[5] = (f16)(b.y * sc); o[6] = (f16)(b.z * sc); o[7] = (f16)(b.w * sc);
    *(half8*)(Bp + (size_t)t * 8) = o;
}

// ---------------- pack x fp32[M][384] -> Xp[rowb][s][kc 4][row 128][8] f16
__global__ void pack_x_kernel(const float* __restrict__ x, f16* __restrict__ Xp) {
    const int b = blockIdx.x;             // rowb*12 + s
    const int s = b % 12;
    const int rowb = b / 12;
    const int t = threadIdx.x;
    const int kc = t & 3, rr = t >> 2;
#pragma unroll
    for (int h = 0; h < 2; ++h) {
        const int row = rr + h * 64;
        const float* sp = x + (size_t)(rowb * 128 + row) * DIM + s * 32 + kc * 8;
        float4 a = *(const float4*)sp;
        float4 bq = *(const float4*)(sp + 4);
        half8 o;
        o[0] = (f16)a.x;  o[1] = (f16)a.y;  o[2] = (f16)a.z;  o[3] = (f16)a.w;
        o[4] = (f16)bq.x; o[5] = (f16)bq.y; o[6] = (f16)bq.z; o[7] = (f16)bq.w;
        *(half8*)(Xp + ((size_t)b * 512 + kc * 128 + row) * 8) = o;
    }
}

// ---------------- one GEMM sub-phase: C(64 x 384) += A(64x384) @ Wp^T, acc per wave 64x96
template<int P>
__device__ __forceinline__ void gemm_phase(const f16* __restrict__ Xp, const f16* __restrict__ Bp,
                                           char* smem, int rowb, int half, int wave,
                                           int g, int c, floatx4 (&acc)[4][6])
{
    const int tid = threadIdx.x;
    auto stA = [&](int s, int buf) {
        const f16* src = Xp + (size_t)(rowb * 12 + s) * 4096
                         + ((size_t)(tid >> 6) * 128 + half * 64 + (tid & 63)) * 8;
        gl_lds16(src, smem + SEG_A + buf * 4096 + tid * 16);
    };
    auto stB = [&](int s, int buf) {
        const f16* base = Bp + (size_t)(P * 12 + s) * 12288;
        char* db = smem + SEG_B + buf * 24576;
#pragma unroll
        for (int r = 0; r < 6; ++r) {
            const int ch = r * 256 + tid;
            gl_lds16(base + (size_t)ch * 8, db + ch * 16);
        }
    };

    stA(0, 0); stB(0, 0);
#pragma unroll
    for (int s = 0; s < 12; ++s) {
        const int buf = s & 1;
        if (s < 11) { stA(s + 1, buf ^ 1); stB(s + 1, buf ^ 1); }
        if (s < 11) asm volatile("s_waitcnt vmcnt(7)" ::: "memory");
        else        asm volatile("s_waitcnt vmcnt(0)" ::: "memory");
        __builtin_amdgcn_sched_barrier(0);
        __builtin_amdgcn_s_barrier();
        __builtin_amdgcn_sched_barrier(0);

        half8 af[4], bf[6];
#pragma unroll
        for (int mi = 0; mi < 4; ++mi)
            af[mi] = *(const half8*)(smem + SEG_A + buf * 4096 + (g * 64 + mi * 16 + c) * 16);
#pragma unroll
        for (int ni = 0; ni < 6; ++ni)
            bf[ni] = *(const half8*)(smem + SEG_B + buf * 24576
                                     + (g * 384 + wave * 96 + ni * 16 + c) * 16);
#pragma unroll
        for (int mi = 0; mi < 4; ++mi)
#pragma unroll
            for (int ni = 0; ni < 6; ++ni)
                acc[mi][ni] = __builtin_amdgcn_mfma_f32_16x16x32_f16(
                    af[mi], bf[ni], acc[mi][ni], 0, 0, 0);

        // drain LDS reads only; gl_lds (vmcnt) stays in flight across the barrier
        asm volatile("s_waitcnt lgkmcnt(0)" ::: "memory");
        __builtin_amdgcn_sched_barrier(0);
        __builtin_amdgcn_s_barrier();
        __builtin_amdgcn_sched_barrier(0);
    }
}

// ---------------- fused qkv + attention: one block = one window, 4 waves, 3 heads/wave
__global__ void __launch_bounds__(256, 1)
fused_kernel(const f16* __restrict__ Xp, const f16* __restrict__ Bp,
             const float* __restrict__ bias_table, f16* __restrict__ pbuf,
             f16* __restrict__ ao)
{
    __shared__ __align__(16) char smem[161792];
    const int w = blockIdx.x;
    const int rowb = w >> 1, half = w & 1;
    const int tid = threadIdx.x;
    const int wave = tid >> 6, lane = tid & 63;
    const int g = lane >> 4, c = lane & 15;

    // bias [12 heads][128] f32 (transposed from [127][12])
    float* bl = (float*)(smem + SEG_BIAS);
    for (int i = tid; i < 127 * HEADS; i += 256) {
        const int pos = i / 12, h = i % 12;
        bl[h * 128 + pos] = bias_table[i];
    }

    floatx4 acc[4][6];

    // ---- K phase ----
#pragma unroll
    for (int mi = 0; mi < 4; ++mi)
#pragma unroll
        for (int ni = 0; ni < 6; ++ni) acc[mi][ni] = floatx4{0.f, 0.f, 0.f, 0.f};
    gemm_phase<1>(Xp, Bp, smem, rowb, half, wave, g, c, acc);
#pragma unroll
    for (int mi = 0; mi < 4; ++mi)
#pragma unroll
        for (int ni = 0; ni < 6; ++ni) {
            const int d = wave * 96 + ni * 16 + c;
#pragma unroll
            for (int j = 0; j < 4; ++j) {
                const int n = mi * 16 + g * 4 + j;
                *(f16*)(smem + SEG_K + qk_off(n, d)) = (f16)acc[mi][ni][j];
            }
        }

    // ---- V phase (transposed store) ----
#pragma unroll
    for (int mi = 0; mi < 4; ++mi)
#pragma unroll
        for (int ni = 0; ni < 6; ++ni) acc[mi][ni] = floatx4{0.f, 0.f, 0.f, 0.f};
    gemm_phase<2>(Xp, Bp, smem, rowb, half, wave, g, c, acc);
#pragma unroll
    for (int mi = 0; mi < 4; ++mi)
#pragma unroll
        for (int ni = 0; ni < 6; ++ni) {
            const int d = wave * 96 + ni * 16 + c;
            const int m0 = mi * 16 + g * 4;
            half4 pk;
#pragma unroll
            for (int j = 0; j < 4; ++j) pk[j] = (f16)acc[mi][ni][j];
            *(half4*)(smem + SEG_V + vt_off(d, m0)) = pk;
        }

    // ---- Q phase (scale pre-folded into weights); store over dead B-staging ----
#pragma unroll
    for (int mi = 0; mi < 4; ++mi)
#pragma unroll
        for (int ni = 0; ni < 6; ++ni) acc[mi][ni] = floatx4{0.f, 0.f, 0.f, 0.f};
    gemm_phase<0>(Xp, Bp, smem, rowb, half, wave, g, c, acc);
#pragma unroll
    for (int mi = 0; mi < 4; ++mi)
#pragma unroll
        for (int ni = 0; ni < 6; ++ni) {
            const int d = wave * 96 + ni * 16 + c;
#pragma unroll
            for (int j = 0; j < 4; ++j) {
                const int n = mi * 16 + g * 4 + j;
                *(f16*)(smem + SEG_B + qk_off(n, d)) = (f16)acc[mi][ni][j];
            }
        }

    // ---- attention: wave-local, heads h = wave*3 + hh ----
    char* pbc = (char*)pbuf + ((size_t)w * 4 + wave) * 8192;   // per-wave P scratch [64][64] f16
#pragma unroll 1
    for (int hh = 0; hh < 3; ++hh) {
        const int h = wave * 3 + hh;
        const int dh = h * HD;

        // QK^T
        half8 qa[4], kb[4];
#pragma unroll
        for (int t = 0; t < 4; ++t) {
            qa[t] = *(const half8*)(smem + SEG_B + qk_off(16 * t + c, dh + 8 * g));
            kb[t] = *(const half8*)(smem + SEG_K + qk_off(16 * t + c, dh + 8 * g));
        }
        floatx4 S[4][4];
#pragma unroll
        for (int nt = 0; nt < 4; ++nt)
#pragma unroll
            for (int mt = 0; mt < 4; ++mt) {
                floatx4 z = {0.f, 0.f, 0.f, 0.f};
                S[nt][mt] = __builtin_amdgcn_mfma_f32_16x16x32_f16(qa[nt], kb[mt], z, 0, 0, 0);
            }

        // bias + row softmax (row = 16nt + 4g + j, cols 16mt + c)
        const float* bh = bl + h * 128 + 63;
#pragma unroll
        for (int nt = 0; nt < 4; ++nt)
#pragma unroll
            for (int j = 0; j < 4; ++j) {
                const int n = 16 * nt + 4 * g + j;
                float mx = -1e30f;
#pragma unroll
                for (int mt = 0; mt < 4; ++mt) {
                    const int m = 16 * mt + c;
                    S[nt][mt][j] += bh[n - m];
                    mx = fmaxf(mx, S[nt][mt][j]);
                }
                mx = fmaxf(mx, __shfl_xor(mx, 1));
                mx = fmaxf(mx, __shfl_xor(mx, 2));
                mx = fmaxf(mx, __shfl_xor(mx, 4));
                mx = fmaxf(mx, __shfl_xor(mx, 8));
                float sum = 0.f;
#pragma unroll
                for (int mt = 0; mt < 4; ++mt) {
                    S[nt][mt][j] = __expf(S[nt][mt][j] - mx);
                    sum += S[nt][mt][j];
                }
                sum += __shfl_xor(sum, 1);
                sum += __shfl_xor(sum, 2);
                sum += __shfl_xor(sum, 4);
                sum += __shfl_xor(sum, 8);
                const float ri = 1.0f / sum;
#pragma unroll
                for (int mt = 0; mt < 4; ++mt) {
                    const int m = 16 * mt + c;
                    *(f16*)(pbc + n * 128 + m * 2) = (f16)(S[nt][mt][j] * ri);
                }
            }

        asm volatile("s_waitcnt vmcnt(0)" ::: "memory");   // P stores complete before reads
        __builtin_amdgcn_sched_barrier(0);

        // PV: O(64x32) = P(64x64) @ v(64x32), k split 2x32
        half8 pa[4][2], vb[2][2];
#pragma unroll
        for (int mi = 0; mi < 4; ++mi)
#pragma unroll
            for (int ks = 0; ks < 2; ++ks)
                pa[mi][ks] = *(const half8*)(pbc + (16 * mi + c) * 128 + (ks * 32 + 8 * g) * 2);
#pragma unroll
        for (int t2 = 0; t2 < 2; ++t2)
#pragma unroll
            for (int ks = 0; ks < 2; ++ks)
                vb[t2][ks] = *(const half8*)(smem + SEG_V + vt_off(dh + 16 * t2 + c, ks * 32 + 8 * g));
        floatx4 O[4][2];
#pragma unroll
        for (int mi = 0; mi < 4; ++mi)
#pragma unroll
            for (int t2 = 0; t2 < 2; ++t2) O[mi][t2] = floatx4{0.f, 0.f, 0.f, 0.f};
#pragma unroll
        for (int ks = 0; ks < 2; ++ks)
#pragma unroll
            for (int mi = 0; mi < 4; ++mi)
#pragma unroll
                for (int t2 = 0; t2 < 2; ++t2)
                    O[mi][t2] = __builtin_amdgcn_mfma_f32_16x16x32_f16(
                        pa[mi][ks], vb[t2][ks], O[mi][t2], 0, 0, 0);

        // write O -> ao[w*64 + n][h*32 + e]
#pragma unroll
        for (int mi = 0; mi < 4; ++mi)
#pragma unroll
            for (int t2 = 0; t2 < 2; ++t2)
#pragma unroll
                for (int j = 0; j < 4; ++j) {
                    const int n = 16 * mi + 4 * g + j;
                    const int e = 16 * t2 + c;
                    ao[((size_t)w * WIN + n) * DIM + dh + e] = (f16)O[mi][t2][j];
                }
    }
}

// ---------------- proj GEMM: out = A[M][384](f16) * Bw[384][384]^T + bias (fp32 out)
__global__ void proj_kernel(const f16* __restrict__ A, const f16* __restrict__ Bw,
                            float* __restrict__ outp, const float* __restrict__ proj_b,
                            int nwg)
{
    __shared__ __align__(16) f16 lds[3][2][4][128][8];   // 48 KB

    int lin = blockIdx.x;
    int nlin = lin;
    if ((nwg & 7) == 0) nlin = (lin & 7) * (nwg >> 3) + (lin >> 3);
    const int colb = nlin % 3, rowb = nlin / 3;
    const int col0 = colb * 128, row0 = rowb * 128;

    const int tid = threadIdx.x;
    const int wave = tid >> 6, lane = tid & 63;
    const int g = lane >> 4, c = lane & 15;
    const int wm = wave >> 1, wn = wave & 1;

    floatx4 acc[4][4] = {};

    auto stage = [&](int t) {
        const int k0 = t * 32;
#pragma unroll
        for (int r = 0; r < 4; ++r) {
            const int u = wave + r * 4;       // 0..15
            const int isB = u >> 3;
            const int uu = u & 7;
            const int kc = uu >> 1, m0 = (uu & 1) * 64;
            const f16* src = (isB ? Bw + (size_t)(col0 + m0 + lane) * DIM
                                  : A  + (size_t)(row0 + m0 + lane) * DIM)
                             + k0 + kc * 8;
            gl_lds16(src, &lds[t % 3][isB][kc][m0][0]);
        }
    };

    stage(0); stage(1);

#pragma unroll
    for (int s = 0; s < 12; ++s) {
        if (s < 11) asm volatile("s_waitcnt vmcnt(4)" ::: "memory");
        else        asm volatile("s_waitcnt vmcnt(0)" ::: "memory");
        asm volatile("s_waitcnt lgkmcnt(0)" ::: "memory");
        __builtin_amdgcn_sched_barrier(0);
        __builtin_amdgcn_s_barrier();
        __builtin_amdgcn_sched_barrier(0);
        if (s < 10) stage(s + 2);

        half8 af[4], bf[4];
#pragma unroll
        for (int i = 0; i < 4; ++i) {
            af[i] = *(const half8*)&lds[s % 3][0][g][wm * 64 + i * 16 + c][0];
            bf[i] = *(const half8*)&lds[s % 3][1][g][wn * 64 + i * 16 + c][0];
        }
#pragma unroll
        for (int mi = 0; mi < 4; ++mi)
#pragma unroll
            for (int ni = 0; ni < 4; ++ni)
                acc[mi][ni] = __builtin_amdgcn_mfma_f32_16x16x32_f16(
                    af[mi], bf[ni], acc[mi][ni], 0, 0, 0);
    }

#pragma unroll
    for (int ni = 0; ni < 4; ++ni) {
        const int d = col0 + wn * 64 + ni * 16 + c;
        const float pb = proj_b[d];
#pragma unroll
        for (int mi = 0; mi < 4; ++mi)
#pragma unroll
            for (int j = 0; j < 4; ++j) {
                const size_t trow = (size_t)row0 + wm * 64 + mi * 16 + g * 4 + j;
                outp[trow * DIM + d] = acc[mi][ni][j] + pb;
            }
    }
}

extern "C" void kernel_launch(void* const* d_in, const int* in_sizes, int n_in,
                              void* d_out, int out_size, void* d_ws, size_t ws_size,
                              hipStream_t stream) {
    const float* x          = (const float*)d_in[0];
    const float* qkv_w      = (const float*)d_in[1];
    const float* proj_w     = (const float*)d_in[2];
    const float* proj_b     = (const float*)d_in[3];
    const float* bias_table = (const float*)d_in[4];
    float* out = (float*)d_out;
    (void)in_sizes; (void)n_in; (void)out_size; (void)ws_size;

    uintptr_t p = (uintptr_t)d_ws;
    auto carve = [&](size_t bytes) -> void* {
        uintptr_t q = p; p += (bytes + 255) & ~(size_t)255; return (void*)q;
    };
    f16* w16_proj = (f16*)carve((size_t)DIM * DIM * 2);
    f16* Bp       = (f16*)carve((size_t)3 * 12 * 4 * 384 * 8 * 2);     // 884736 B
    f16* Xp       = (f16*)carve((size_t)NWIN * WIN * DIM * 2);         // 201 MB
    f16* ao       = (f16*)carve((size_t)NWIN * WIN * DIM * 2);         // 201 MB
    f16* pbuf     = (f16*)carve((size_t)NWIN * 4 * 8192);              // 134 MB

    cvt_kernel<<<dim3(64), dim3(256), 0, stream>>>(proj_w, w16_proj, (long)(DIM * DIM / 4));
    pack_w_kernel<<<dim3(216), dim3(256), 0, stream>>>(qkv_w, Bp);

    const int rowbs = NWIN / 2;
    pack_x_kernel<<<dim3(rowbs * 12), dim3(256), 0, stream>>>(x, Xp);

    fused_kernel<<<dim3(NWIN), dim3(256), 0, stream>>>(Xp, Bp, bias_table, pbuf, ao);

    const int nwg2 = rowbs * 3;
    proj_kernel<<<dim3(nwg2), dim3(256), 0, stream>>>(ao, w16_proj, out, proj_b, nwg2);
}

// Round 11
// 915.661 us; speedup vs baseline: 1.1316x; 1.1316x over previous
//
#include <hip/hip_runtime.h>
#include <stdint.h>

#define DIM 384
#define WIN 64
#define HEADS 12
#define HD 32
#define NWIN 4096

typedef _Float16 f16;
typedef unsigned int u32;
typedef _Float16 half8 __attribute__((ext_vector_type(8)));
typedef _Float16 half4 __attribute__((ext_vector_type(4)));
typedef float floatx4 __attribute__((ext_vector_type(4)));

#define AS1 __attribute__((address_space(1)))
#define AS3 __attribute__((address_space(3)))

__device__ __forceinline__ void gl_lds16(const void* g, void* l) {
    __builtin_amdgcn_global_load_lds((const AS1 u32*)g, (AS3 u32*)l, 16, 0, 0);
}

// ---------------- fp32 -> fp16 convert (proj weights) ----------------
__global__ void cvt_kernel(const float* __restrict__ in, f16* __restrict__ out, long n4) {
    long i = (long)blockIdx.x * blockDim.x + threadIdx.x;
    const long stride = (long)gridDim.x * blockDim.x;
    for (; i < n4; i += stride) {
        float4 v = ((const float4*)in)[i];
        half4 h;
        h[0] = (f16)v.x; h[1] = (f16)v.y; h[2] = (f16)v.z; h[3] = (f16)v.w;
        ((half4*)out)[i] = h;
    }
}

// ---------------- pack qkv_w fp32[1152][384] -> Bp[colb 6][s 12][kc 4][u 192][8] f16
__global__ void pack_w_kernel(const float* __restrict__ w, f16* __restrict__ Bp) {
    const int t = blockIdx.x * 256 + threadIdx.x;      // 55296 chunks
    const int colb = t / 9216;
    const int r1 = t % 9216;
    const int s = r1 / 768;
    const int r2 = r1 % 768;
    const int kc = r2 / 192, u = r2 % 192;
    const float* sp = w + (size_t)(colb * 192 + u) * DIM + s * 32 + kc * 8;
    float4 a = *(const float4*)sp;
    float4 b = *(const float4*)(sp + 4);
    half8 o;
    o[0] = (f16)a.x; o[1] = (f16)a.y; o[2] = (f16)a.z; o[3] = (f16)a.w;
    o[4] = (f16)b.x; o[5] = (f16)b.y; o[6] = (f16)b.z; o[7] = (f16)b.w;
    *(half8*)(Bp + (size_t)t * 8) = o;
}

// ---------------- pack x fp32[M][384] -> Xp[rowb][s][kc 4][row 128][8] f16
__global__ void pack_x_kernel(const float* __restrict__ x, f16* __restrict__ Xp) {
    const int b = blockIdx.x;             // rowb*12 + s
    const int s = b % 12;
    const int rowb = b / 12;
    const int t = threadIdx.x;
    const int kc = t & 3, rr = t >> 2;
#pragma unroll
    for (int h = 0; h < 2; ++h) {
        const int row = rr + h * 64;
        const float* sp = x + (size_t)(rowb * 128 + row) * DIM + s * 32 + kc * 8;
        float4 a = *(const float4*)sp;
        float4 bq = *(const float4*)(sp + 4);
        half8 o;
        o[0] = (f16)a.x;  o[1] = (f16)a.y;  o[2] = (f16)a.z;  o[3] = (f16)a.w;
        o[4] = (f16)bq.x; o[5] = (f16)bq.y; o[6] = (f16)bq.z; o[7] = (f16)bq.w;
        *(half8*)(Xp + ((size_t)b * 512 + kc * 128 + row) * 8) = o;
    }
}

// ---------------- QKV GEMM: 256x192 block, BK=64, 8 waves (wave tile 64x96, acc 4x6)
// A 2-buf 1-ahead (4 gl_lds/thr), B 3-buf 2-ahead (3 gl_lds/thr); head vmcnt(3)
// drains {B(t),A(t)}, keeps B(t+1) in flight. 6 barriers total. LDS 136 KB.
__global__ void __launch_bounds__(512, 2)
qkv_kernel(const f16* __restrict__ Xp, const f16* __restrict__ Bp,
           f16* __restrict__ q_arr, f16* __restrict__ k_arr,
           f16* __restrict__ v_int, int nwg)
{
    __shared__ __align__(16) f16 ldsA[2][16384];   // 64 KB : [buf][slab4][kc4][row128][8]
    __shared__ __align__(16) f16 ldsB[3][12288];   // 72 KB : [buf][ss2][kc4][u192][8]

    int lin = blockIdx.x;
    int nlin = lin;
    if ((nwg & 7) == 0) nlin = (lin & 7) * (nwg >> 3) + (lin >> 3);
    const int colb = nlin % 6, rowb = nlin / 6;

    const int tid = threadIdx.x;
    const int wave = tid >> 6, lane = tid & 63;
    const int g = lane >> 4, c = lane & 15;
    const int wm = wave >> 1, wn = wave & 1;       // 4 x 2 wave grid

    floatx4 acc[4][6] = {};

    auto stageA = [&](int t) {     // 32 KB: rows 256 x k 64
        f16* da = &ldsA[t & 1][0];
#pragma unroll
        for (int r = 0; r < 4; ++r) {               // slab = rg*2 + ss
            const int rg = r >> 1, ss = r & 1;
            const f16* src = Xp + ((size_t)(2 * rowb + rg) * 12 + (2 * t + ss)) * 4096
                             + (size_t)tid * 8;
            gl_lds16(src, da + r * 4096 + tid * 8);
        }
    };
    auto stageB = [&](int t) {     // 24 KB: u 192 x k 64
        f16* db = &ldsB[t % 3][0];
#pragma unroll
        for (int r = 0; r < 3; ++r) {
            const int ch = r * 512 + tid;           // 0..1535
            const int ss = ch / 768, rem = ch % 768;
            const f16* src = Bp + ((size_t)colb * 12 + (2 * t + ss)) * 6144 + (size_t)rem * 8;
            gl_lds16(src, db + ch * 8);
        }
    };

    // prologue: queue = [A(0)4, B(0)3, B(1)3]
    stageA(0); stageB(0); stageB(1);

#pragma unroll
    for (int t = 0; t < 6; ++t) {
        // steady head queue: [B(t)3, A(t)4, B(t+1)3] -> vmcnt(3) drains B(t)+A(t)
        if (t < 5) asm volatile("s_waitcnt vmcnt(3)" ::: "memory");
        else       asm volatile("s_waitcnt vmcnt(0)" ::: "memory");
        __builtin_amdgcn_sched_barrier(0);
        __builtin_amdgcn_s_barrier();
        __builtin_amdgcn_sched_barrier(0);
        if (t < 5) stageA(t + 1);   // writes ldsA[(t+1)&1] != read buf
        if (t < 4) stageB(t + 2);   // writes ldsB[(t+2)%3] != read buf

        const f16* ab = &ldsA[t & 1][0];
        const f16* bb = &ldsB[t % 3][0];
#pragma unroll
        for (int ks = 0; ks < 2; ++ks) {
            half8 af[4], bf[6];
#pragma unroll
            for (int mi = 0; mi < 4; ++mi) {
                const int row = wm * 64 + mi * 16 + c;
                const int slab = (row >> 7) * 2 + ks;
                af[mi] = *(const half8*)(ab + slab * 4096 + g * 1024 + (row & 127) * 8);
            }
#pragma unroll
            for (int ni = 0; ni < 6; ++ni) {
                const int u = wn * 96 + ni * 16 + c;
                bf[ni] = *(const half8*)(bb + ks * 6144 + g * 1536 + u * 8);
            }
#pragma unroll
            for (int mi = 0; mi < 4; ++mi)
#pragma unroll
                for (int ni = 0; ni < 6; ++ni)
                    acc[mi][ni] = __builtin_amdgcn_mfma_f32_16x16x32_f16(
                        af[mi], bf[ni], acc[mi][ni], 0, 0, 0);
        }
    }

    // epilogue: scatter q/k row-major per (b,h), v interleaved for attn B-frags
    const int which = colb >> 1;           // 0=q 1=k 2=v
    const int dbase = (colb & 1) * 192;
    const int b0 = rowb * 4 + wm;          // BM=256 = 4 windows; wave wm owns one
    if (which < 2) {
        f16* dst = which ? k_arr : q_arr;
        const float sc = which ? 1.0f : 0.17677669529663687f;  // 32^-0.5 folded into q
#pragma unroll
        for (int ni = 0; ni < 6; ++ni) {
            const int d = dbase + wn * 96 + ni * 16 + c;
            const int h = d >> 5, e = d & 31;
            f16* base = dst + (size_t)(b0 * HEADS + h) * (WIN * HD) + e;
#pragma unroll
            for (int mi = 0; mi < 4; ++mi)
#pragma unroll
                for (int j = 0; j < 4; ++j) {
                    const int n = mi * 16 + g * 4 + j;
                    base[(size_t)n * HD] = (f16)(acc[mi][ni][j] * sc);
                }
        }
    } else {
#pragma unroll
        for (int ni = 0; ni < 6; ++ni) {
            const int d = dbase + wn * 96 + ni * 16 + c;
            const int h = d >> 5, e = d & 31;
            f16* vb = v_int + (size_t)(b0 * HEADS + h) * (WIN * HD);
#pragma unroll
            for (int mi = 0; mi < 4; ++mi) {
                const int n0 = mi * 16 + g * 4;
                half4 pk;
#pragma unroll
                for (int j = 0; j < 4; ++j) pk[j] = (f16)acc[mi][ni][j];
                *(half4*)(vb + (n0 >> 3) * 256 + e * 8 + (n0 & 7)) = pk;
            }
        }
    }
}

// ---------------- proj GEMM: out = A[M][384](f16) * Bw[384][384]^T + bias (fp32 out)
__global__ void proj_kernel(const f16* __restrict__ A, const f16* __restrict__ Bw,
                            float* __restrict__ outp, const float* __restrict__ proj_b,
                            int nwg)
{
    __shared__ __align__(16) f16 lds[3][2][4][128][8];   // 48 KB

    int lin = blockIdx.x;
    int nlin = lin;
    if ((nwg & 7) == 0) nlin = (lin & 7) * (nwg >> 3) + (lin >> 3);
    const int colb = nlin % 3, rowb = nlin / 3;
    const int col0 = colb * 128, row0 = rowb * 128;

    const int tid = threadIdx.x;
    const int wave = tid >> 6, lane = tid & 63;
    const int g = lane >> 4, c = lane & 15;
    const int wm = wave >> 1, wn = wave & 1;

    floatx4 acc[4][4] = {};

    auto stage = [&](int t) {
        const int k0 = t * 32;
#pragma unroll
        for (int r = 0; r < 4; ++r) {
            const int u = wave + r * 4;       // 0..15
            const int isB = u >> 3;
            const int uu = u & 7;
            const int kc = uu >> 1, m0 = (uu & 1) * 64;
            const f16* src = (isB ? Bw + (size_t)(col0 + m0 + lane) * DIM
                                  : A  + (size_t)(row0 + m0 + lane) * DIM)
                             + k0 + kc * 8;
            gl_lds16(src, &lds[t % 3][isB][kc][m0][0]);
        }
    };

    stage(0); stage(1);

#pragma unroll
    for (int s = 0; s < 12; ++s) {
        if (s < 11) asm volatile("s_waitcnt vmcnt(4)" ::: "memory");
        else        asm volatile("s_waitcnt vmcnt(0)" ::: "memory");
        asm volatile("s_waitcnt lgkmcnt(0)" ::: "memory");
        __builtin_amdgcn_sched_barrier(0);
        __builtin_amdgcn_s_barrier();
        __builtin_amdgcn_sched_barrier(0);
        if (s < 10) stage(s + 2);

        half8 af[4], bf[4];
#pragma unroll
        for (int i = 0; i < 4; ++i) {
            af[i] = *(const half8*)&lds[s % 3][0][g][wm * 64 + i * 16 + c][0];
            bf[i] = *(const half8*)&lds[s % 3][1][g][wn * 64 + i * 16 + c][0];
        }
#pragma unroll
        for (int mi = 0; mi < 4; ++mi)
#pragma unroll
            for (int ni = 0; ni < 4; ++ni)
                acc[mi][ni] = __builtin_amdgcn_mfma_f32_16x16x32_f16(
                    af[mi], bf[ni], acc[mi][ni], 0, 0, 0);
    }

#pragma unroll
    for (int ni = 0; ni < 4; ++ni) {
        const int d = col0 + wn * 64 + ni * 16 + c;
        const float pb = proj_b[d];
#pragma unroll
        for (int mi = 0; mi < 4; ++mi)
#pragma unroll
            for (int j = 0; j < 4; ++j) {
                const size_t trow = (size_t)row0 + wm * 64 + mi * 16 + g * 4 + j;
                outp[trow * DIM + d] = acc[mi][ni][j] + pb;
            }
    }
}

// ---------------- attention: one block per (window, head) ----------------
__global__ void attn_kernel(const f16* __restrict__ q_arr, const f16* __restrict__ k_arr,
                            const f16* __restrict__ v_int,
                            const float* __restrict__ bias_table,
                            f16* __restrict__ attn_out)
{
    const int bid = blockIdx.x;
    const int bw = bid / HEADS, h = bid % HEADS;
    const f16* q = q_arr + (size_t)bid * (WIN * HD);
    const f16* k = k_arr + (size_t)bid * (WIN * HD);
    const f16* v = v_int + (size_t)bid * (WIN * HD);

    const int tid = threadIdx.x;
    const int w = tid >> 6, lane = tid & 63;
    const int g = lane >> 4, c = lane & 15;

    __shared__ float bias_lds[2 * WIN - 1];
    __shared__ __align__(16) f16 p_lds[8][64][8];   // P in A-frag-interleaved layout

    for (int i = tid; i < 2 * WIN - 1; i += 256)
        bias_lds[i] = bias_table[(size_t)i * HEADS + h];
    __syncthreads();

    // S = Q K^T : wave w owns rows 16w..16w+15, all 64 cols
    half8 qa = *(const half8*)(q + (16 * w + c) * HD + g * 8);
    floatx4 s[4];
#pragma unroll
    for (int t = 0; t < 4; ++t) {
        half8 kb = *(const half8*)(k + (16 * t + c) * HD + g * 8);
        floatx4 z = {};
        s[t] = __builtin_amdgcn_mfma_f32_16x16x32_f16(qa, kb, z, 0, 0, 0);
    }

    // bias + row softmax
    float pr[4][4];
#pragma unroll
    for (int j = 0; j < 4; ++j) {
        const int n = 16 * w + g * 4 + j;
        float mx = -1e30f;
#pragma unroll
        for (int t = 0; t < 4; ++t) {
            const int m = 16 * t + c;
            pr[j][t] = s[t][j] + bias_lds[n - m + 63];
            mx = fmaxf(mx, pr[j][t]);
        }
        mx = fmaxf(mx, __shfl_xor(mx, 1));
        mx = fmaxf(mx, __shfl_xor(mx, 2));
        mx = fmaxf(mx, __shfl_xor(mx, 4));
        mx = fmaxf(mx, __shfl_xor(mx, 8));
        float sum = 0.f;
#pragma unroll
        for (int t = 0; t < 4; ++t) { pr[j][t] = __expf(pr[j][t] - mx); sum += pr[j][t]; }
        sum += __shfl_xor(sum, 1);
        sum += __shfl_xor(sum, 2);
        sum += __shfl_xor(sum, 4);
        sum += __shfl_xor(sum, 8);
        const float r = 1.0f / sum;
#pragma unroll
        for (int t = 0; t < 4; ++t) {
            const int m = 16 * t + c;
            p_lds[m >> 3][n][m & 7] = (f16)(pr[j][t] * r);
        }
    }
    __syncthreads();

    // O = P V
    half8 pa0 = *(const half8*)&p_lds[g][16 * w + c][0];
    half8 pa1 = *(const half8*)&p_lds[4 + g][16 * w + c][0];
    floatx4 o[2];
#pragma unroll
    for (int t = 0; t < 2; ++t) {
        half8 vb0 = *(const half8*)(v + g * 256 + (16 * t + c) * 8);
        half8 vb1 = *(const half8*)(v + (4 + g) * 256 + (16 * t + c) * 8);
        floatx4 z = {};
        o[t] = __builtin_amdgcn_mfma_f32_16x16x32_f16(pa0, vb0, z, 0, 0, 0);
        o[t] = __builtin_amdgcn_mfma_f32_16x16x32_f16(pa1, vb1, o[t], 0, 0, 0);
    }
#pragma unroll
    for (int t = 0; t < 2; ++t)
#pragma unroll
        for (int j = 0; j < 4; ++j) {
            const int n = 16 * w + g * 4 + j;
            attn_out[((size_t)bw * WIN + n) * DIM + h * HD + 16 * t + c] = (f16)o[t][j];
        }
}

extern "C" void kernel_launch(void* const* d_in, const int* in_sizes, int n_in,
                              void* d_out, int out_size, void* d_ws, size_t ws_size,
                              hipStream_t stream) {
    const float* x          = (const float*)d_in[0];
    const float* qkv_w      = (const float*)d_in[1];
    const float* proj_w     = (const float*)d_in[2];
    const float* proj_b     = (const float*)d_in[3];
    const float* bias_table = (const float*)d_in[4];
    float* out = (float*)d_out;
    (void)in_sizes; (void)n_in; (void)out_size;

    uintptr_t p = (uintptr_t)d_ws;
    auto carve = [&](size_t bytes) -> void* {
        uintptr_t q = p; p += (bytes + 255) & ~(size_t)255; return (void*)q;
    };
    f16* w16_proj = (f16*)carve((size_t)DIM * DIM * 2);
    f16* Bp       = (f16*)carve((size_t)6 * 12 * 768 * 8 * 2);   // 884736 B
    const size_t fixed = p - (uintptr_t)d_ws;

    // per-window ws: Xp + q + k + v + ao = 5 * 49152 B
    int CB = NWIN;
    while (CB > 16 && fixed + (size_t)CB * 245760 + 4096 > ws_size) CB >>= 1;

    f16* Xp = (f16*)carve((size_t)CB * WIN * DIM * 2);
    f16* qa = (f16*)carve((size_t)CB * HEADS * WIN * HD * 2);
    f16* ka = (f16*)carve((size_t)CB * HEADS * WIN * HD * 2);
    f16* vi = (f16*)carve((size_t)CB * HEADS * WIN * HD * 2);
    f16* ao = (f16*)carve((size_t)CB * WIN * DIM * 2);

    cvt_kernel<<<dim3(64), dim3(256), 0, stream>>>(proj_w, w16_proj, (long)(DIM * DIM / 4));
    pack_w_kernel<<<dim3(216), dim3(256), 0, stream>>>(qkv_w, Bp);

    for (int c0 = 0; c0 < NWIN; c0 += CB) {
        const float* xc = x + (size_t)c0 * WIN * DIM;
        const int rowbs = CB / 2;                       // 128-row granules

        pack_x_kernel<<<dim3(rowbs * 12), dim3(256), 0, stream>>>(xc, Xp);

        const int nwg1 = (CB * WIN / 256) * 6;          // 256-row blocks x 6 col-panels
        qkv_kernel<<<dim3(nwg1), dim3(512), 0, stream>>>(Xp, Bp, qa, ka, vi, nwg1);

        attn_kernel<<<dim3(CB * HEADS), dim3(256), 0, stream>>>(qa, ka, vi, bias_table, ao);

        const int nwg2 = rowbs * 3;
        proj_kernel<<<dim3(nwg2), dim3(256), 0, stream>>>(ao, w16_proj,
                                                          out + (size_t)c0 * WIN * DIM, proj_b, nwg2);
    }
}

// Round 12
// 852.915 us; speedup vs baseline: 1.2149x; 1.0736x over previous
//
#include <hip/hip_runtime.h>
#include <stdint.h>

#define DIM 384
#define WIN 64
#define HEADS 12
#define HD 32
#define NWIN 4096

typedef _Float16 f16;
typedef unsigned int u32;
typedef _Float16 half8 __attribute__((ext_vector_type(8)));
typedef _Float16 half4 __attribute__((ext_vector_type(4)));
typedef float floatx4 __attribute__((ext_vector_type(4)));

#define AS1 __attribute__((address_space(1)))
#define AS3 __attribute__((address_space(3)))

__device__ __forceinline__ void gl_lds16(const void* g, void* l) {
    __builtin_amdgcn_global_load_lds((const AS1 u32*)g, (AS3 u32*)l, 16, 0, 0);
}

// ---------------- fp32 -> fp16 convert (proj weights) ----------------
__global__ void cvt_kernel(const float* __restrict__ in, f16* __restrict__ out, long n4) {
    long i = (long)blockIdx.x * blockDim.x + threadIdx.x;
    const long stride = (long)gridDim.x * blockDim.x;
    for (; i < n4; i += stride) {
        float4 v = ((const float4*)in)[i];
        half4 h;
        h[0] = (f16)v.x; h[1] = (f16)v.y; h[2] = (f16)v.z; h[3] = (f16)v.w;
        ((half4*)out)[i] = h;
    }
}

// ---------------- pack qkv_w fp32[1152][384] -> Bp[colb 6][s 12][kc 4][u 192][8] f16
__global__ void pack_w_kernel(const float* __restrict__ w, f16* __restrict__ Bp) {
    const int t = blockIdx.x * 256 + threadIdx.x;      // 55296 chunks
    const int colb = t / 9216;
    const int r1 = t % 9216;
    const int s = r1 / 768;
    const int r2 = r1 % 768;
    const int kc = r2 / 192, u = r2 % 192;
    const float* sp = w + (size_t)(colb * 192 + u) * DIM + s * 32 + kc * 8;
    float4 a = *(const float4*)sp;
    float4 b = *(const float4*)(sp + 4);
    half8 o;
    o[0] = (f16)a.x; o[1] = (f16)a.y; o[2] = (f16)a.z; o[3] = (f16)a.w;
    o[4] = (f16)b.x; o[5] = (f16)b.y; o[6] = (f16)b.z; o[7] = (f16)b.w;
    *(half8*)(Bp + (size_t)t * 8) = o;
}

// ---------------- QKV GEMM: 256x192 block, BK=64, 8 waves (wave tile 64x96, acc 4x6)
// A: fp32 x -> reg (8x float4) -> f16 XOR-swizzled LDS dbuf (in-kernel cvt, no pack_x).
// B: packed panels via 3-buf global_load_lds, 2-ahead.
// writeA(t+1)'s implicit vmcnt wait (oldest 8 = A-loads) also drains B(t+1); B(t+2)
// stays in flight across the barrier. launch_bounds(512,2) = 256-reg cap (no spill).
__global__ void __launch_bounds__(512, 2)
qkv_kernel(const float* __restrict__ X32, const f16* __restrict__ Bp,
           f16* __restrict__ q_arr, f16* __restrict__ k_arr,
           f16* __restrict__ v_int, int nwg)
{
    __shared__ __align__(16) f16 xa[2][2][256][32];   // 64 KB : A f16 [buf][ks][row][32] XOR
    __shared__ __align__(16) f16 ldsB[3][12288];      // 72 KB : [buf][ss2][kc4][u192][8]

    int lin = blockIdx.x;
    int nlin = lin;
    if ((nwg & 7) == 0) nlin = (lin & 7) * (nwg >> 3) + (lin >> 3);
    const int colb = nlin % 6, rowb = nlin / 6;
    const int row0 = rowb * 256;

    const int tid = threadIdx.x;
    const int wave = tid >> 6, lane = tid & 63;
    const int g = lane >> 4, c = lane & 15;
    const int wm = wave >> 1, wn = wave & 1;       // 4 x 2 wave grid

    floatx4 acc[4][6] = {};
    float4 rA[8];

    auto loadA = [&](int t) {                      // 256 rows x 64 k fp32 -> 8 float4/thr
#pragma unroll
        for (int r = 0; r < 8; ++r) {
            const int i = r * 512 + tid;           // 0..4095
            const int row = i >> 4, kq = i & 15;
            rA[r] = *(const float4*)(X32 + (size_t)(row0 + row) * DIM + t * 64 + kq * 4);
        }
    };
    auto writeA = [&](int t) {
#pragma unroll
        for (int r = 0; r < 8; ++r) {
            const int i = r * 512 + tid;
            const int row = i >> 4, kq = i & 15;
            const int ks = kq >> 3, kq2 = kq & 7;
            const int sl = (kq2 >> 1) ^ ((row >> 1) & 3);
            half4 h;
            h[0] = (f16)rA[r].x; h[1] = (f16)rA[r].y;
            h[2] = (f16)rA[r].z; h[3] = (f16)rA[r].w;
            *(half4*)&xa[t & 1][ks][row][sl * 8 + (kq2 & 1) * 4] = h;
        }
    };
    auto stageB = [&](int t) {                     // 24 KB: u 192 x k 64
        f16* db = &ldsB[t % 3][0];
#pragma unroll
        for (int r = 0; r < 3; ++r) {
            const int ch = r * 512 + tid;          // 0..1535
            const int ss = ch / 768, rem = ch % 768;
            const f16* src = Bp + ((size_t)colb * 12 + (2 * t + ss)) * 6144 + (size_t)rem * 8;
            gl_lds16(src, db + ch * 8);
        }
    };

    // prologue: issue order A(0)8, B(0)3, B(1)3; writeA(0) waits A(0) -> vmcnt(6)
    loadA(0); stageB(0); stageB(1);
    writeA(0);
    loadA(1);

#pragma unroll
    for (int t = 0; t < 6; ++t) {
        // t=0: outstanding [B(0)3,B(1)3,A(1)8]=14 -> vmcnt(11) drains B(0).
        // t>=1: B(t) already drained by writeA(t) last iter; vmcnt(11) is a no-op.
        asm volatile("s_waitcnt vmcnt(11)" ::: "memory");
        asm volatile("s_waitcnt lgkmcnt(0)" ::: "memory");
        __builtin_amdgcn_sched_barrier(0);
        __builtin_amdgcn_s_barrier();
        __builtin_amdgcn_sched_barrier(0);
        if (t < 4) stageB(t + 2);                  // writes ldsB[(t+2)%3] != read buf

        const f16* bb = &ldsB[t % 3][0];
#pragma unroll
        for (int ks = 0; ks < 2; ++ks) {
            half8 af[4], bf[6];
#pragma unroll
            for (int mi = 0; mi < 4; ++mi) {
                const int row = wm * 64 + mi * 16 + c;
                const int sl = g ^ ((row >> 1) & 3);
                af[mi] = *(const half8*)&xa[t & 1][ks][row][sl * 8];
            }
#pragma unroll
            for (int ni = 0; ni < 6; ++ni) {
                const int u = wn * 96 + ni * 16 + c;
                bf[ni] = *(const half8*)(bb + ks * 6144 + g * 1536 + u * 8);
            }
#pragma unroll
            for (int mi = 0; mi < 4; ++mi)
#pragma unroll
                for (int ni = 0; ni < 6; ++ni)
                    acc[mi][ni] = __builtin_amdgcn_mfma_f32_16x16x32_f16(
                        af[mi], bf[ni], acc[mi][ni], 0, 0, 0);
        }
        // writeA(t+1): waits A(t+1) (oldest) -> vmcnt(3); drains B(t+1), keeps B(t+2)
        if (t < 5) writeA(t + 1);
        if (t < 4) loadA(t + 2);
    }

    // epilogue: scatter q/k row-major per (b,h), v interleaved for attn B-frags
    const int which = colb >> 1;           // 0=q 1=k 2=v
    const int dbase = (colb & 1) * 192;
    const int b0 = rowb * 4 + wm;          // BM=256 = 4 windows; wave wm owns one
    if (which < 2) {
        f16* dst = which ? k_arr : q_arr;
        const float sc = which ? 1.0f : 0.17677669529663687f;  // 32^-0.5 folded into q
#pragma unroll
        for (int ni = 0; ni < 6; ++ni) {
            const int d = dbase + wn * 96 + ni * 16 + c;
            const int h = d >> 5, e = d & 31;
            f16* base = dst + (size_t)(b0 * HEADS + h) * (WIN * HD) + e;
#pragma unroll
            for (int mi = 0; mi < 4; ++mi)
#pragma unroll
                for (int j = 0; j < 4; ++j) {
                    const int n = mi * 16 + g * 4 + j;
                    base[(size_t)n * HD] = (f16)(acc[mi][ni][j] * sc);
                }
        }
    } else {
#pragma unroll
        for (int ni = 0; ni < 6; ++ni) {
            const int d = dbase + wn * 96 + ni * 16 + c;
            const int h = d >> 5, e = d & 31;
            f16* vb = v_int + (size_t)(b0 * HEADS + h) * (WIN * HD);
#pragma unroll
            for (int mi = 0; mi < 4; ++mi) {
                const int n0 = mi * 16 + g * 4;
                half4 pk;
#pragma unroll
                for (int j = 0; j < 4; ++j) pk[j] = (f16)acc[mi][ni][j];
                *(half4*)(vb + (n0 >> 3) * 256 + e * 8 + (n0 & 7)) = pk;
            }
        }
    }
}

// ---------------- proj GEMM: out = A[M][384](f16) * Bw[384][384]^T + bias (fp32 out)
__global__ void proj_kernel(const f16* __restrict__ A, const f16* __restrict__ Bw,
                            float* __restrict__ outp, const float* __restrict__ proj_b,
                            int nwg)
{
    __shared__ __align__(16) f16 lds[3][2][4][128][8];   // 48 KB

    int lin = blockIdx.x;
    int nlin = lin;
    if ((nwg & 7) == 0) nlin = (lin & 7) * (nwg >> 3) + (lin >> 3);
    const int colb = nlin % 3, rowb = nlin / 3;
    const int col0 = colb * 128, row0 = rowb * 128;

    const int tid = threadIdx.x;
    const int wave = tid >> 6, lane = tid & 63;
    const int g = lane >> 4, c = lane & 15;
    const int wm = wave >> 1, wn = wave & 1;

    floatx4 acc[4][4] = {};

    auto stage = [&](int t) {
        const int k0 = t * 32;
#pragma unroll
        for (int r = 0; r < 4; ++r) {
            const int u = wave + r * 4;       // 0..15
            const int isB = u >> 3;
            const int uu = u & 7;
            const int kc = uu >> 1, m0 = (uu & 1) * 64;
            const f16* src = (isB ? Bw + (size_t)(col0 + m0 + lane) * DIM
                                  : A  + (size_t)(row0 + m0 + lane) * DIM)
                             + k0 + kc * 8;
            gl_lds16(src, &lds[t % 3][isB][kc][m0][0]);
        }
    };

    stage(0); stage(1);

#pragma unroll
    for (int s = 0; s < 12; ++s) {
        if (s < 11) asm volatile("s_waitcnt vmcnt(4)" ::: "memory");
        else        asm volatile("s_waitcnt vmcnt(0)" ::: "memory");
        asm volatile("s_waitcnt lgkmcnt(0)" ::: "memory");
        __builtin_amdgcn_sched_barrier(0);
        __builtin_amdgcn_s_barrier();
        __builtin_amdgcn_sched_barrier(0);
        if (s < 10) stage(s + 2);

        half8 af[4], bf[4];
#pragma unroll
        for (int i = 0; i < 4; ++i) {
            af[i] = *(const half8*)&lds[s % 3][0][g][wm * 64 + i * 16 + c][0];
            bf[i] = *(const half8*)&lds[s % 3][1][g][wn * 64 + i * 16 + c][0];
        }
#pragma unroll
        for (int mi = 0; mi < 4; ++mi)
#pragma unroll
            for (int ni = 0; ni < 4; ++ni)
                acc[mi][ni] = __builtin_amdgcn_mfma_f32_16x16x32_f16(
                    af[mi], bf[ni], acc[mi][ni], 0, 0, 0);
    }

#pragma unroll
    for (int ni = 0; ni < 4; ++ni) {
        const int d = col0 + wn * 64 + ni * 16 + c;
        const float pb = proj_b[d];
#pragma unroll
        for (int mi = 0; mi < 4; ++mi)
#pragma unroll
            for (int j = 0; j < 4; ++j) {
                const size_t trow = (size_t)row0 + wm * 64 + mi * 16 + g * 4 + j;
                outp[trow * DIM + d] = acc[mi][ni][j] + pb;
            }
    }
}

// ---------------- attention: one block per (window, head) ----------------
__global__ void attn_kernel(const f16* __restrict__ q_arr, const f16* __restrict__ k_arr,
                            const f16* __restrict__ v_int,
                            const float* __restrict__ bias_table,
                            f16* __restrict__ attn_out)
{
    const int bid = blockIdx.x;
    const int bw = bid / HEADS, h = bid % HEADS;
    const f16* q = q_arr + (size_t)bid * (WIN * HD);
    const f16* k = k_arr + (size_t)bid * (WIN * HD);
    const f16* v = v_int + (size_t)bid * (WIN * HD);

    const int tid = threadIdx.x;
    const int w = tid >> 6, lane = tid & 63;
    const int g = lane >> 4, c = lane & 15;

    __shared__ float bias_lds[2 * WIN - 1];
    __shared__ __align__(16) f16 p_lds[8][64][8];   // P in A-frag-interleaved layout

    for (int i = tid; i < 2 * WIN - 1; i += 256)
        bias_lds[i] = bias_table[(size_t)i * HEADS + h];
    __syncthreads();

    // S = Q K^T : wave w owns rows 16w..16w+15, all 64 cols
    half8 qa = *(const half8*)(q + (16 * w + c) * HD + g * 8);
    floatx4 s[4];
#pragma unroll
    for (int t = 0; t < 4; ++t) {
        half8 kb = *(const half8*)(k + (16 * t + c) * HD + g * 8);
        floatx4 z = {};
        s[t] = __builtin_amdgcn_mfma_f32_16x16x32_f16(qa, kb, z, 0, 0, 0);
    }

    // bias + row softmax
    float pr[4][4];
#pragma unroll
    for (int j = 0; j < 4; ++j) {
        const int n = 16 * w + g * 4 + j;
        float mx = -1e30f;
#pragma unroll
        for (int t = 0; t < 4; ++t) {
            const int m = 16 * t + c;
            pr[j][t] = s[t][j] + bias_lds[n - m + 63];
            mx = fmaxf(mx, pr[j][t]);
        }
        mx = fmaxf(mx, __shfl_xor(mx, 1));
        mx = fmaxf(mx, __shfl_xor(mx, 2));
        mx = fmaxf(mx, __shfl_xor(mx, 4));
        mx = fmaxf(mx, __shfl_xor(mx, 8));
        float sum = 0.f;
#pragma unroll
        for (int t = 0; t < 4; ++t) { pr[j][t] = __expf(pr[j][t] - mx); sum += pr[j][t]; }
        sum += __shfl_xor(sum, 1);
        sum += __shfl_xor(sum, 2);
        sum += __shfl_xor(sum, 4);
        sum += __shfl_xor(sum, 8);
        const float r = 1.0f / sum;
#pragma unroll
        for (int t = 0; t < 4; ++t) {
            const int m = 16 * t + c;
            p_lds[m >> 3][n][m & 7] = (f16)(pr[j][t] * r);
        }
    }
    __syncthreads();

    // O = P V
    half8 pa0 = *(const half8*)&p_lds[g][16 * w + c][0];
    half8 pa1 = *(const half8*)&p_lds[4 + g][16 * w + c][0];
    floatx4 o[2];
#pragma unroll
    for (int t = 0; t < 2; ++t) {
        half8 vb0 = *(const half8*)(v + g * 256 + (16 * t + c) * 8);
        half8 vb1 = *(const half8*)(v + (4 + g) * 256 + (16 * t + c) * 8);
        floatx4 z = {};
        o[t] = __builtin_amdgcn_mfma_f32_16x16x32_f16(pa0, vb0, z, 0, 0, 0);
        o[t] = __builtin_amdgcn_mfma_f32_16x16x32_f16(pa1, vb1, o[t], 0, 0, 0);
    }
#pragma unroll
    for (int t = 0; t < 2; ++t)
#pragma unroll
        for (int j = 0; j < 4; ++j) {
            const int n = 16 * w + g * 4 + j;
            attn_out[((size_t)bw * WIN + n) * DIM + h * HD + 16 * t + c] = (f16)o[t][j];
        }
}

extern "C" void kernel_launch(void* const* d_in, const int* in_sizes, int n_in,
                              void* d_out, int out_size, void* d_ws, size_t ws_size,
                              hipStream_t stream) {
    const float* x          = (const float*)d_in[0];
    const float* qkv_w      = (const float*)d_in[1];
    const float* proj_w     = (const float*)d_in[2];
    const float* proj_b     = (const float*)d_in[3];
    const float* bias_table = (const float*)d_in[4];
    float* out = (float*)d_out;
    (void)in_sizes; (void)n_in; (void)out_size;

    uintptr_t p = (uintptr_t)d_ws;
    auto carve = [&](size_t bytes) -> void* {
        uintptr_t q = p; p += (bytes + 255) & ~(size_t)255; return (void*)q;
    };
    f16* w16_proj = (f16*)carve((size_t)DIM * DIM * 2);
    f16* Bp       = (f16*)carve((size_t)6 * 12 * 768 * 8 * 2);   // 884736 B
    const size_t fixed = p - (uintptr_t)d_ws;

    // per-window ws: q + k + v + ao = 4 * 49152 B
    int CB = NWIN;
    while (CB > 16 && fixed + (size_t)CB * 196608 + 4096 > ws_size) CB >>= 1;

    f16* qa = (f16*)carve((size_t)CB * HEADS * WIN * HD * 2);
    f16* ka = (f16*)carve((size_t)CB * HEADS * WIN * HD * 2);
    f16* vi = (f16*)carve((size_t)CB * HEADS * WIN * HD * 2);
    f16* ao = (f16*)carve((size_t)CB * WIN * DIM * 2);

    cvt_kernel<<<dim3(64), dim3(256), 0, stream>>>(proj_w, w16_proj, (long)(DIM * DIM / 4));
    pack_w_kernel<<<dim3(216), dim3(256), 0, stream>>>(qkv_w, Bp);

    for (int c0 = 0; c0 < NWIN; c0 += CB) {
        const float* xc = x + (size_t)c0 * WIN * DIM;

        const int nwg1 = (CB * WIN / 256) * 6;          // 256-row blocks x 6 col-panels
        qkv_kernel<<<dim3(nwg1), dim3(512), 0, stream>>>(xc, Bp, qa, ka, vi, nwg1);

        attn_kernel<<<dim3(CB * HEADS), dim3(256), 0, stream>>>(qa, ka, vi, bias_table, ao);

        const int nwg2 = (CB * WIN / 128) * 3;
        proj_kernel<<<dim3(nwg2), dim3(256), 0, stream>>>(ao, w16_proj,
                                                          out + (size_t)c0 * WIN * DIM, proj_b, nwg2);
    }
}